// Round 15
// baseline (1129.819 us; speedup 1.0000x reference)
//
#include <hip/hip_runtime.h>
#include <cstddef>

#define HW 16384           // 128*128
#define NELEM 819200       // 2*25*HW

// XT layout: [b][row 142][ks 2][half 2][px 144][8ch]
#define XT_ROW 4608
#define XT_KS  2304
#define XT_HALF 1152

typedef _Float16 f16x8 __attribute__((ext_vector_type(8)));
typedef _Float16 f16x4 __attribute__((ext_vector_type(4)));
typedef _Float16 f16x2 __attribute__((ext_vector_type(2)));
typedef float    f32x16 __attribute__((ext_vector_type(16)));

#define MFMA32(a, b, c) __builtin_amdgcn_mfma_f32_32x32x16_f16((a), (b), (c), 0, 0, 0)

#if __has_builtin(__builtin_amdgcn_fdot2)
#define HAS_FDOT2 1
#else
#define HAS_FDOT2 0
#endif

__device__ __forceinline__ float sp_f(float x) {
    return fmaxf(x, 0.f) + log1pf(expf(-fabsf(x)));
}
__device__ __forceinline__ float sig_f(float x) {
    return 1.f / (1.f + expf(-x));
}

// ---------------- front-end prepack kernels ----------------
__global__ __launch_bounds__(256) void xpack0_kernel(
    const float* __restrict__ x, _Float16* __restrict__ x0)
{
    const int p = blockIdx.x * 256 + threadIdx.x;   // < 262144
    const int b = p >> 17, rem = p & 131071;
    const int z = rem >> 14, pix = rem & 16383;
    const int y = pix >> 7, xx = pix & 127;
    const size_t sb = ((size_t)b * 3 * 8 + z) << 14;
    f16x4 v;
    v[0] = (_Float16)x[sb + pix];
    v[1] = (_Float16)x[sb + (8ull << 14) + pix];
    v[2] = (_Float16)x[sb + (16ull << 14) + pix];
    v[3] = (_Float16)0.f;
    *(f16x4*)(x0 + (((size_t)(b * 8 + z) * 134 + y + 3) * 136 + xx + 3) * 4) = v;
}

__global__ __launch_bounds__(256) void repack_w00_kernel(
    const float* __restrict__ w, _Float16* __restrict__ wt)
{
    const int idx = blockIdx.x * 256 + threadIdx.x;   // < 50176
    const int j  = idx & 7;
    const int m  = (idx >> 3) & 31;
    const int h  = (idx >> 8) & 1;
    const int kk = (idx >> 9) & 1;
    const int tapb = idx >> 10;                       // dz*7+dy, < 49
    const int dz = tapb / 7, dy = tapb - dz * 7;
    const int ic = j & 3, dxl = j >> 2;
    const int dx = kk * 4 + h * 2 + dxl;
    float v = 0.f;
    if (m < 25 && ic < 3 && dx < 7)
        v = w[(((m * 3 + ic) * 7 + dz) * 7 + dy) * 7 + dx];
    wt[idx] = (_Float16)v;
}

__global__ __launch_bounds__(256) void xpack1_kernel(
    const _Float16* __restrict__ b0p, _Float16* __restrict__ x1)
{
    const int p = blockIdx.x * 256 + threadIdx.x;   // < 262144
    const int b = p >> 17, rem = p & 131071;
    const int z = rem >> 14, pix = rem & 16383;
    const int y = pix >> 7, xx = pix & 127;
    float s = 0.f;
    #pragma unroll
    for (int g = 0; g < 25; ++g) s += (float)b0p[(size_t)g * 262144 + p];
    x1[(((size_t)(b * 8 + z) * 134 + y + 3) * 136 + xx + 3) * 2] = (_Float16)s;
}

__global__ __launch_bounds__(256) void repack_w1_kernel(
    const float* __restrict__ w, _Float16* __restrict__ wt)
{
    const int idx = blockIdx.x * 256 + threadIdx.x;   // < 25088
    const int j = idx & 7;
    const int m = (idx >> 3) & 31;
    const int h = (idx >> 8) & 1;
    const int tapb = idx >> 9;                        // < 49
    const int dz = tapb / 7, dy = tapb - dz * 7;
    const int c2 = j & 1, dx = h * 4 + (j >> 1);
    float v = 0.f;
    if (m < 25 && c2 == 0 && dx < 7)
        v = w[((m * 7 + dz) * 7 + dy) * 7 + dx];
    wt[idx] = (_Float16)v;
}

// ---------------- conv00 via MFMA: 3ch -> 25ch, writes halo-4-padded f16 planes ----
__global__ __launch_bounds__(128) void conv3d00_mfma(
    const _Float16* __restrict__ x0, const _Float16* __restrict__ wt0,
    _Float16* __restrict__ apad)
{
    const int g = blockIdx.x;
    const int b = g >> 10;
    const int zo = (g >> 7) & 7;
    const int y = g & 127;
    const int tid = threadIdx.x;
    const int wv = tid >> 6;
    const int lane = tid & 63;
    const int n = lane & 31;
    const int h = lane >> 5;
    const int xc = wv << 6;

    f32x16 acc0, acc1;
    #pragma unroll
    for (int i = 0; i < 16; ++i) { acc0[i] = 0.f; acc1[i] = 0.f; }

    for (int dz = 0; dz < 7; ++dz) {
        const int zin = zo + dz - 3;
        if (zin < 0 || zin >= 8) continue;
        const _Float16* xpl = x0 + (size_t)(b * 8 + zin) * (134 * 136 * 4);
        #pragma unroll
        for (int dy = 0; dy < 7; ++dy) {
            const _Float16* xr = xpl + (size_t)(y + dy) * (136 * 4);
            const _Float16* wb = wt0 + (size_t)((dz * 7 + dy) * 2) * 512 + h * 256 + n * 8;
            f16x8 a0 = *(const f16x8*)(wb);
            f16x8 a1 = *(const f16x8*)(wb + 512);
            const _Float16* bp = xr + (size_t)(xc + n + 2 * h) * 4;
            f16x8 b00 = *(const f16x8*)(bp);
            f16x8 b01 = *(const f16x8*)(bp + 16);
            f16x8 b10 = *(const f16x8*)(bp + 128);
            f16x8 b11 = *(const f16x8*)(bp + 144);
            acc0 = MFMA32(a0, b00, acc0);
            acc1 = MFMA32(a0, b10, acc1);
            acc0 = MFMA32(a1, b01, acc0);
            acc1 = MFMA32(a1, b11, acc1);
        }
    }
    _Float16* ob = apad + (size_t)((b * 25) * 8 + zo) * 18496
                 + (size_t)(y + 4) * 136 + 4 + xc + n;
    #pragma unroll
    for (int r = 0; r < 16; ++r) {
        const int row = (r & 3) + 8 * (r >> 2) + 4 * h;
        if (row < 25) {
            ob[(size_t)row * 147968]      = (_Float16)acc0[r];
            ob[(size_t)row * 147968 + 32] = (_Float16)acc1[r];
        }
    }
}

// ---------------- conv0: 25ch -> 1ch, direct-global f16 reads, fdot2, f16 partials ----
__global__ __launch_bounds__(128) void conv3d0_direct(
    const _Float16* __restrict__ apad, const float* __restrict__ wgt,
    _Float16* __restrict__ out)
{
    const int y0 = blockIdx.x * 16;
    const int ic = blockIdx.y;
    const int b  = blockIdx.z >> 3;
    const int zo = blockIdx.z & 7;
    const int tid = threadIdx.x, tx = tid & 15, ty = tid >> 4;

    float acc0[8] = {0,0,0,0,0,0,0,0};
    float acc1[8] = {0,0,0,0,0,0,0,0};
    const float* wb0 = wgt + ic * 343;

    for (int dz = 0; dz < 7; ++dz) {
        const int zin = zo + dz - 3;
        if (zin < 0 || zin >= 8) continue;
        const _Float16* pl = apad + (size_t)((b * 25 + ic) * 8 + zin) * 18496
                           + (size_t)(y0 + (ty << 1) + 1) * 136 + (tx << 3);
        const float* wb = wb0 + dz * 49;
#if HAS_FDOT2
        f16x2 wpn[4], wpo[4];
        #pragma unroll
        for (int j = 0; j <= 7; ++j) {
            f16x8 r0 = *(const f16x8*)(pl + (size_t)j * 136);
            f16x8 r1 = *(const f16x8*)(pl + (size_t)j * 136 + 8);
            _Float16 rr[16];
            #pragma unroll
            for (int i = 0; i < 8; ++i) { rr[i] = r0[i]; rr[8 + i] = r1[i]; }
            f16x2 pr[14];
            #pragma unroll
            for (int i = 0; i < 14; ++i) { pr[i][0] = rr[i + 1]; pr[i][1] = rr[i + 2]; }
            if (j <= 6) {
                #pragma unroll
                for (int p = 0; p < 3; ++p) {
                    wpn[p][0] = (_Float16)wb[j * 7 + 2 * p];
                    wpn[p][1] = (_Float16)wb[j * 7 + 2 * p + 1];
                }
                wpn[3][0] = (_Float16)wb[j * 7 + 6];
                wpn[3][1] = (_Float16)0.f;
            }
            #pragma unroll
            for (int k = 0; k < 8; ++k) {
                if (j <= 6) {
                    #pragma unroll
                    for (int p = 0; p < 4; ++p)
                        acc0[k] = __builtin_amdgcn_fdot2(wpn[p], pr[k + 2 * p], acc0[k], false);
                }
                if (j >= 1) {
                    #pragma unroll
                    for (int p = 0; p < 4; ++p)
                        acc1[k] = __builtin_amdgcn_fdot2(wpo[p], pr[k + 2 * p], acc1[k], false);
                }
            }
            #pragma unroll
            for (int p = 0; p < 4; ++p) wpo[p] = wpn[p];
        }
#else
        float wn[7], wo[7];
        #pragma unroll
        for (int j = 0; j <= 7; ++j) {
            f16x8 r0 = *(const f16x8*)(pl + (size_t)j * 136);
            f16x8 r1 = *(const f16x8*)(pl + (size_t)j * 136 + 8);
            float rrf[16];
            #pragma unroll
            for (int i = 0; i < 8; ++i) { rrf[i] = (float)r0[i]; rrf[8 + i] = (float)r1[i]; }
            if (j <= 6) {
                #pragma unroll
                for (int d = 0; d < 7; ++d) wn[d] = wb[j * 7 + d];
            }
            #pragma unroll
            for (int dx = 0; dx < 7; ++dx) {
                if (j <= 6) {
                    float w0 = wn[dx];
                    #pragma unroll
                    for (int k = 0; k < 8; ++k) acc0[k] = fmaf(rrf[dx + k + 1], w0, acc0[k]);
                }
                if (j >= 1) {
                    float w1 = wo[dx];
                    #pragma unroll
                    for (int k = 0; k < 8; ++k) acc1[k] = fmaf(rrf[dx + k + 1], w1, acc1[k]);
                }
            }
            #pragma unroll
            for (int d = 0; d < 7; ++d) wo[d] = wn[d];
        }
#endif
    }
    _Float16* op = out + (size_t)ic * 262144
              + (((size_t)(b * 8 + zo)) << 14) + ((size_t)(y0 + (ty << 1)) << 7) + (tx << 3);
    f16x8 o0, o1;
    #pragma unroll
    for (int k = 0; k < 8; ++k) { o0[k] = (_Float16)acc0[k]; o1[k] = (_Float16)acc1[k]; }
    *(f16x8*)op = o0;
    *(f16x8*)(op + 128) = o1;
}

// ---------------- conv1 via MFMA: 1ch -> 25ch, bias+square fused ----------------
__global__ __launch_bounds__(128) void conv3d1_mfma(
    const _Float16* __restrict__ x1, const _Float16* __restrict__ wt1,
    const float* __restrict__ bias, float* __restrict__ out)
{
    const int g = blockIdx.x;
    const int b = g >> 10;
    const int zo = (g >> 7) & 7;
    const int y = g & 127;
    const int tid = threadIdx.x;
    const int wv = tid >> 6;
    const int lane = tid & 63;
    const int n = lane & 31;
    const int h = lane >> 5;
    const int xc = wv << 6;

    f32x16 acc0, acc1;
    #pragma unroll
    for (int i = 0; i < 16; ++i) { acc0[i] = 0.f; acc1[i] = 0.f; }

    for (int dz = 0; dz < 7; ++dz) {
        const int zin = zo + dz - 3;
        if (zin < 0 || zin >= 8) continue;
        const _Float16* xpl = x1 + (size_t)(b * 8 + zin) * (134 * 136 * 2);
        #pragma unroll
        for (int dy = 0; dy < 7; ++dy) {
            const _Float16* wb = wt1 + (size_t)(dz * 7 + dy) * 512 + h * 256 + n * 8;
            f16x8 a0 = *(const f16x8*)(wb);
            const _Float16* bp = xpl + ((size_t)(y + dy) * 136 + xc + n) * 2 + h * 8;
            f16x8 b0 = *(const f16x8*)(bp);
            f16x8 b1 = *(const f16x8*)(bp + 64);
            acc0 = MFMA32(a0, b0, acc0);
            acc1 = MFMA32(a0, b1, acc1);
        }
    }
    float* ob = out + ((((size_t)b * 25) * 8 + zo) << 14) + (y << 7) + xc + n;
    #pragma unroll
    for (int r = 0; r < 16; ++r) {
        const int row = (r & 3) + 8 * (r >> 2) + 4 * h;
        if (row < 25) {
            float v0 = acc0[r] + bias[row];
            float v1 = acc1[r] + bias[row];
            ob[(size_t)row * 131072]      = v0 * v0;
            ob[(size_t)row * 131072 + 32] = v1 * v1;
        }
    }
}

// ---------------- weight repack for 15x15 (A-frag) ----------------
__global__ __launch_bounds__(256) void repack_w_kernel(
    const float* __restrict__ w, _Float16* __restrict__ wt)
{
    const int idx = blockIdx.x * 256 + threadIdx.x;   // < 230400
    const int j    = idx & 7;
    const int m    = (idx >> 3) & 31;
    const int half = (idx >> 8) & 1;
    const int ks   = (idx >> 9) & 1;
    const int t    = idx >> 10;                       // t = ky*15+kx, < 225
    const int ic   = ks * 16 + half * 8 + j;
    float v = 0.f;
    if (m < 25 && ic < 25) v = w[(m * 25 + ic) * 225 + t];
    wt[idx] = (_Float16)v;
}

// ---------------- 2D conv 15x15 v5: kg=4, B-row register rolling, dbuf LDS A ----
template<int NKY>
__device__ __forceinline__ void conv15_core_v5(
    const _Float16* __restrict__ xb, const _Float16* __restrict__ wtk,
    _Float16* lA, int tid, int bRow0, int xg, int n, int half,
    f32x16& accA, f32x16& accB, f32x16& accC, f32x16& accD)
{
    #pragma unroll
    for (int j = 0; j <= NKY; ++j) {
        if (j < NKY) {
            if (j > 0) __syncthreads();
            _Float16* dst = lA + (size_t)(j & 1) * 15360;
            const _Float16* src = wtk + (size_t)j * 15360;
            #pragma unroll
            for (int p = 0; p < 8; ++p) {
                const int g = p * 256 + tid;
                if (g < 1920)
                    *(f16x8*)(dst + (size_t)g * 8) = *(const f16x8*)(src + (size_t)g * 8);
            }
            __syncthreads();
        }
        const _Float16* br = xb + (size_t)(bRow0 + j) * XT_ROW
                           + (size_t)half * XT_HALF + (size_t)(xg + n) * 8;
        const _Float16* lc = lA + (size_t)(j & 1) * 15360 + half * 256 + n * 8;
        const _Float16* lp = lA + (size_t)((j - 1) & 1) * 15360 + half * 256 + n * 8;
        #pragma unroll
        for (int kx = 0; kx < 15; ++kx) {
            const _Float16* p0 = br + kx * 8;
            f16x8 b00 = *(const f16x8*)(p0);
            f16x8 b01 = *(const f16x8*)(p0 + XT_KS);
            f16x8 b10 = *(const f16x8*)(p0 + 256);
            f16x8 b11 = *(const f16x8*)(p0 + XT_KS + 256);
            if (j < NKY) {
                f16x8 a0 = *(const f16x8*)(lc + kx * 1024);
                f16x8 a1 = *(const f16x8*)(lc + kx * 1024 + 512);
                accA = MFMA32(a0, b00, accA); accA = MFMA32(a1, b01, accA);
                accB = MFMA32(a0, b10, accB); accB = MFMA32(a1, b11, accB);
            }
            if (j >= 1) {
                f16x8 q0 = *(const f16x8*)(lp + kx * 1024);
                f16x8 q1 = *(const f16x8*)(lp + kx * 1024 + 512);
                accC = MFMA32(q0, b00, accC); accC = MFMA32(q1, b01, accC);
                accD = MFMA32(q0, b10, accD); accD = MFMA32(q1, b11, accD);
            }
        }
    }
}

__global__ __launch_bounds__(256) void conv2d15_mfma(
    const _Float16* __restrict__ xt, const _Float16* __restrict__ wt,
    _Float16* __restrict__ cph)
{
    const int blk = blockIdx.x;          // 64: b*32 + rq
    const int b   = blk >> 5;
    const int rq  = blk & 31;
    const int kg  = blockIdx.y;          // 0..3

    __shared__ __align__(16) _Float16 lA[30720];   // 2 x 30 KB double buffer

    const int tid  = threadIdx.x;
    const int w    = tid >> 6;
    const int lane = tid & 63;
    const int n    = lane & 31;
    const int half = lane >> 5;
    const int xg   = (w & 1) << 6;
    const int y0w  = rq * 4 + ((w >> 1) << 1);

    f32x16 accA, accB, accC, accD;
    #pragma unroll
    for (int i = 0; i < 16; ++i) { accA[i] = 0.f; accB[i] = 0.f; accC[i] = 0.f; accD[i] = 0.f; }

    const int ky0 = (kg < 3) ? kg * 4 : 12;
    const _Float16* xb = xt + (size_t)(b * 142) * XT_ROW;
    const _Float16* wtk = wt + (size_t)ky0 * 15360;
    const int bRow0 = y0w + ky0;

    if (kg < 3) conv15_core_v5<4>(xb, wtk, lA, tid, bRow0, xg, n, half, accA, accB, accC, accD);
    else        conv15_core_v5<3>(xb, wtk, lA, tid, bRow0, xg, n, half, accA, accB, accC, accD);

    _Float16* ob = cph + (size_t)kg * NELEM + (((size_t)b * 25) << 14) + (y0w << 7) + xg + n;
    #pragma unroll
    for (int r = 0; r < 16; ++r) {
        const int oc = (r & 3) + 8 * (r >> 2) + 4 * half;
        if (oc < 25) {
            _Float16* p = ob + ((size_t)oc << 14);
            p[0]   = (_Float16)accA[r];
            p[32]  = (_Float16)accB[r];
            p[128] = (_Float16)accC[r];
            p[160] = (_Float16)accD[r];
        }
    }
}

// ---------------- BN stats stage 1: sum 4 f16 partials -> f16 CS + PS (shuffle) ----
__global__ __launch_bounds__(256) void bnstats1_kernel(
    const _Float16* __restrict__ cph, _Float16* __restrict__ csh,
    float2* __restrict__ ps)
{
    const int c = blockIdx.x;     // 25
    const int s = blockIdx.y;     // 8
    const int tid = threadIdx.x;
    float s1 = 0.f, s2 = 0.f;
    #pragma unroll
    for (int bb = 0; bb < 2; ++bb) {
        const size_t plane = ((size_t)(bb * 25 + c)) << 14;
        #pragma unroll
        for (int i = 0; i < 2; ++i) {
            const size_t e = plane + ((size_t)(s * 512 + tid + i * 256)) * 4;
            float4 v = make_float4(0.f, 0.f, 0.f, 0.f);
            #pragma unroll
            for (int p = 0; p < 4; ++p) {
                f16x4 q = *(const f16x4*)(cph + (size_t)p * NELEM + e);
                v.x += (float)q[0]; v.y += (float)q[1]; v.z += (float)q[2]; v.w += (float)q[3];
            }
            f16x4 o;
            o[0] = (_Float16)v.x; o[1] = (_Float16)v.y; o[2] = (_Float16)v.z; o[3] = (_Float16)v.w;
            *(f16x4*)(csh + e) = o;
            s1 += v.x + v.y + v.z + v.w;
            s2 += v.x * v.x + v.y * v.y + v.z * v.z + v.w * v.w;
        }
    }
    #pragma unroll
    for (int off = 32; off; off >>= 1) { s1 += __shfl_down(s1, off); s2 += __shfl_down(s2, off); }
    __shared__ float a1[4], a2[4];
    if ((tid & 63) == 0) { a1[tid >> 6] = s1; a2[tid >> 6] = s2; }
    __syncthreads();
    if (tid == 0)
        ps[c * 8 + s] = make_float2(a1[0] + a1[1] + a1[2] + a1[3],
                                    a2[0] + a2[1] + a2[2] + a2[3]);
}

// ---------------- fused ns1, channel-split 2 slots: XT = f16(ns1) ----------------
// 256 blocks x 256 thr; slot = tid>>7 (0: ch0-15 / chunks 0-1, 1: ch16-24 / chunks 2-3)
__global__ __launch_bounds__(256) void nsg_kernel(
    const float* __restrict__ y, const float* __restrict__ h,
    const _Float16* __restrict__ csh, const float2* __restrict__ ps,
    const float* __restrict__ gw, const float* __restrict__ gb,
    const float* __restrict__ alpha, const float* __restrict__ mu,
    _Float16* __restrict__ xt, int t)
{
    __shared__ float sc[25], sh[25];
    const int tid = threadIdx.x;
    if (tid < 25) {
        float s1 = 0.f, s2 = 0.f;
        #pragma unroll
        for (int s = 0; s < 8; ++s) { float2 v = ps[tid * 8 + s]; s1 += v.x; s2 += v.y; }
        const float m = s1 * (1.f / 32768.f);
        const float var = fmaxf(s2 * (1.f / 32768.f) - m * m, 0.f);
        const float scv = gw[tid] * rsqrtf(var + 1e-3f);
        sc[tid] = scv;
        sh[tid] = gb[tid] - m * scv;
    }
    __syncthreads();
    const int slot = tid >> 7;
    const int p = blockIdx.x * 128 + (tid & 127);   // < 32768
    const int b = p >> 14, pix = p & (HW - 1);
    const size_t base = (((size_t)b * 25) << 14) + pix;
    const int c0 = slot ? 16 : 0, c1 = slot ? 25 : 16;
    __align__(16) _Float16 xv[16];
    #pragma unroll 16
    for (int c = c0; c < c1; ++c) {
        const size_t idx = base + ((size_t)c << 14);
        const float yv = y[(((size_t)(b * 25 + c) * 8 + t) << 14) + pix];
        const float c1n = (float)csh[idx] * sc[c] + sh[c];
        const float pre = c1n * (alpha[c] * h[idx] + mu[c]);
        xv[c - c0] = (_Float16)sp_f(yv - sp_f(pre));
    }
    if (slot) {
        #pragma unroll
        for (int c = 9; c < 16; ++c) xv[c] = (_Float16)0.f;
    }
    const int yy = pix >> 7, xx = pix & 127;
    _Float16* xp = xt + (size_t)(b * 142 + yy + 7) * XT_ROW + (size_t)(xx + 7) * 8
                 + (size_t)slot * XT_KS;
    *(float4*)(xp)           = ((const float4*)xv)[0];
    *(float4*)(xp + XT_HALF) = ((const float4*)xv)[1];
}

// ---------------- fused hnew + both gates, channel-split 2 slots w/ LDS staging ----
__global__ __launch_bounds__(256) void hg_kernel(
    float* __restrict__ h, const _Float16* __restrict__ csh,
    const float2* __restrict__ ps, const float* __restrict__ gw,
    const float* __restrict__ gb, const float* __restrict__ kappa,
    const float* __restrict__ gp, const float* __restrict__ wmix,
    const float* __restrict__ u1w, const float* __restrict__ u1b,
    const float* __restrict__ u2w, const float* __restrict__ u2b,
    _Float16* __restrict__ xt)
{
    __shared__ float sc[25], sh[25];
    __shared__ float nvs[128 * 26];
    __shared__ float hvs[128 * 26];
    const int tid = threadIdx.x;
    if (tid < 25) {
        float s1 = 0.f, s2 = 0.f;
        #pragma unroll
        for (int s = 0; s < 8; ++s) { float2 v = ps[tid * 8 + s]; s1 += v.x; s2 += v.y; }
        const float m = s1 * (1.f / 32768.f);
        const float var = fmaxf(s2 * (1.f / 32768.f) - m * m, 0.f);
        const float scv = gw[tid] * rsqrtf(var + 1e-3f);
        sc[tid] = scv;
        sh[tid] = gb[tid] - m * scv;
    }
    const int slot = tid >> 7;
    const int lpix = tid & 127;
    const int p = blockIdx.x * 128 + lpix;   // < 32768
    const int b = p >> 14, pix = p & (HW - 1);
    const size_t base = (((size_t)b * 25) << 14) + pix;
    const int yy = pix >> 7, xx = pix & 127;
    _Float16* xp = xt + (size_t)(b * 142 + yy + 7) * XT_ROW + (size_t)(xx + 7) * 8
                 + (size_t)slot * XT_KS;
    const int c0 = slot ? 16 : 0, c1 = slot ? 25 : 16;
    float* nvr = nvs + lpix * 26;
    float* hvr = hvs + lpix * 26;

    // Phase A: nv from XT (own chunks) -> LDS
    __align__(16) _Float16 nvh[16];
    ((float4*)nvh)[0] = *(const float4*)(xp);
    ((float4*)nvh)[1] = *(const float4*)(xp + XT_HALF);
    #pragma unroll 16
    for (int c = c0; c < c1; ++c) nvr[c] = (float)nvh[c - c0];
    __syncthreads();

    // Phase B: gate2 from LDS nv; hnew for own channels; stage hv
    #pragma unroll 16
    for (int c = c0; c < c1; ++c) {
        float acc = u2b[c];
        #pragma unroll
        for (int ic = 0; ic < 25; ++ic) acc += u2w[c * 25 + ic] * nvr[ic];
        const float g = sig_f(acc);
        const size_t idx = base + ((size_t)c << 14);
        const float c2n = (float)csh[idx] * sc[c] + sh[c];
        const float n = nvr[c];
        const float h2 = sp_f(kappa[c] * n + gp[c] * c2n + wmix[c] * n * c2n);
        const float hn = sp_f((1.f - g) * h[idx] + g * h2);
        h[idx] = hn;
        hvr[c] = hn;
    }
    __syncthreads();

    // Phase C: gate1 from LDS hv; write XT chunks
    __align__(16) _Float16 xv[16];
    #pragma unroll 16
    for (int c = c0; c < c1; ++c) {
        float acc = u1b[c];
        #pragma unroll
        for (int ic = 0; ic < 25; ++ic) acc += u1w[c * 25 + ic] * hvr[ic];
        xv[c - c0] = (_Float16)(hvr[c] * sig_f(acc));
    }
    if (slot) {
        #pragma unroll
        for (int c = 9; c < 16; ++c) xv[c] = (_Float16)0.f;
    }
    *(float4*)(xp)           = ((const float4*)xv)[0];
    *(float4*)(xp + XT_HALF) = ((const float4*)xv)[1];
}

// ---------------- head: BN stats over H (f32) ----------------
__global__ __launch_bounds__(256) void bnstats_head_kernel(
    const float* __restrict__ x, float2* __restrict__ ps)
{
    const int c = blockIdx.x;     // 25
    const int s = blockIdx.y;     // 8
    const int tid = threadIdx.x;
    float s1 = 0.f, s2 = 0.f;
    #pragma unroll
    for (int bb = 0; bb < 2; ++bb) {
        const size_t plane = ((size_t)(bb * 25 + c)) << 14;
        const float4* p0 = (const float4*)(x + plane) + s * 512;
        #pragma unroll
        for (int i = 0; i < 2; ++i) {
            float4 v = p0[tid + i * 256];
            s1 += v.x + v.y + v.z + v.w;
            s2 += v.x * v.x + v.y * v.y + v.z * v.z + v.w * v.w;
        }
    }
    #pragma unroll
    for (int off = 32; off; off >>= 1) { s1 += __shfl_down(s1, off); s2 += __shfl_down(s2, off); }
    __shared__ float a1[4], a2[4];
    if ((tid & 63) == 0) { a1[tid >> 6] = s1; a2[tid >> 6] = s2; }
    __syncthreads();
    if (tid == 0)
        ps[c * 8 + s] = make_float2(a1[0] + a1[1] + a1[2] + a1[3],
                                    a2[0] + a2[1] + a2[2] + a2[3]);
}

// ---------------- fused BN finalize + bn_out + avgpool2 + fc partial dot ----------------
__global__ __launch_bounds__(256) void fc1_kernel(
    const float* __restrict__ h, const float2* __restrict__ ps,
    const float* __restrict__ gw, const float* __restrict__ gb,
    const float* __restrict__ fcw, float2* __restrict__ part)
{
    __shared__ float sc[25], sh[25];
    const int tid = threadIdx.x;
    if (tid < 25) {
        float s1 = 0.f, s2 = 0.f;
        #pragma unroll
        for (int s = 0; s < 8; ++s) { float2 v = ps[tid * 8 + s]; s1 += v.x; s2 += v.y; }
        const float m = s1 * (1.f / 32768.f);
        const float var = fmaxf(s2 * (1.f / 32768.f) - m * m, 0.f);
        const float scv = gw[tid] * rsqrtf(var + 1e-3f);
        sc[tid] = scv;
        sh[tid] = gb[tid] - m * scv;
    }
    __syncthreads();
    const int i = blockIdx.x * 256 + tid;   // < 204800
    int px = i & 63;
    int t = i >> 6;
    int py = t & 63; t >>= 6;               // t = b*25 + c
    int c = t >= 25 ? t - 25 : t;
    const float* hp = h + ((size_t)t << 14);
    const int y0 = py << 1, xg = px << 1;
    float s = hp[(y0 << 7) + xg] + hp[(y0 << 7) + xg + 1]
            + hp[((y0 + 1) << 7) + xg] + hp[((y0 + 1) << 7) + xg + 1];
    const float o = 0.25f * s * sc[c] + sh[c];
    float p0 = o * fcw[i];
    float p1 = o * fcw[204800 + i];
    #pragma unroll
    for (int off = 32; off; off >>= 1) { p0 += __shfl_down(p0, off); p1 += __shfl_down(p1, off); }
    __shared__ float a0[4], a1[4];
    if ((tid & 63) == 0) { a0[tid >> 6] = p0; a1[tid >> 6] = p1; }
    __syncthreads();
    if (tid == 0)
        part[blockIdx.x] = make_float2(a0[0] + a0[1] + a0[2] + a0[3],
                                       a1[0] + a1[1] + a1[2] + a1[3]);
}

__global__ __launch_bounds__(256) void fc2_kernel(
    const float2* __restrict__ part, const float* __restrict__ fcb, float* __restrict__ out)
{
    const int tid = threadIdx.x;
    float s0 = 0.f, s1 = 0.f;
    for (int i = tid; i < 800; i += 256) { float2 v = part[i]; s0 += v.x; s1 += v.y; }
    #pragma unroll
    for (int off = 32; off; off >>= 1) { s0 += __shfl_down(s0, off); s1 += __shfl_down(s1, off); }
    __shared__ float a0[4], a1[4];
    if ((tid & 63) == 0) { a0[tid >> 6] = s0; a1[tid >> 6] = s1; }
    __syncthreads();
    if (tid == 0) {
        out[0] = sig_f(a0[0] + a0[1] + a0[2] + a0[3] + fcb[0]);
        out[1] = sig_f(a1[0] + a1[1] + a1[2] + a1[3] + fcb[1]);
    }
}

extern "C" void kernel_launch(void* const* d_in, const int* in_sizes, int n_in,
                              void* d_out, int out_size, void* d_ws, size_t ws_size,
                              hipStream_t stream)
{
    const float* x        = (const float*)d_in[0];
    const float* conv00_w = (const float*)d_in[1];
    const float* conv0_w  = (const float*)d_in[2];
    const float* conv1_w  = (const float*)d_in[3];
    const float* conv1_b  = (const float*)d_in[4];
    const float* u1_w     = (const float*)d_in[5];
    const float* u1_b     = (const float*)d_in[6];
    const float* u2_w     = (const float*)d_in[7];
    const float* u2_b     = (const float*)d_in[8];
    const float* w_inh    = (const float*)d_in[9];
    const float* w_exc    = (const float*)d_in[10];
    const float* alpha    = (const float*)d_in[11];
    const float* mu       = (const float*)d_in[12];
    const float* gamma_p  = (const float*)d_in[13];
    const float* kappa    = (const float*)d_in[14];
    const float* w_mix    = (const float*)d_in[15];
    const float* bn1_w    = (const float*)d_in[16];
    const float* bn1_b    = (const float*)d_in[17];
    const float* bn3_w    = (const float*)d_in[18];
    const float* bn3_b    = (const float*)d_in[19];
    const float* bn_out_w = (const float*)d_in[20];
    const float* bn_out_b = (const float*)d_in[21];
    const float* fc4_w    = (const float*)d_in[22];
    const float* fc4_b    = (const float*)d_in[23];

    float* ws = (float*)d_ws;
    // layout (float offsets):
    float* Y    = ws;                        // [0, 6,553,600): B0p(f16) early, then Y
    float* R    = ws + 6553600;              // front-end: APAD; then H + CPH(4x f16) + CSH
    float* X0f  = ws + 13107200;             // X0: 583,424 fl
    float* X1f  = ws + 13690624;             // X1: 291,712 fl
    float* WT0f = ws + 13982336;             // 25,088 fl
    float* WT1cf= ws + 14007424;             // 12,544 fl
    float* WT1f = ws + 14019968;             // 115,200 fl
    float* WT2f = ws + 14135168;             // 115,200 fl
    float* XTf  = ws + 14250368;             // 654,336 fl
    float* PART = ws + 14904704;             // 1600
    float* PS   = PART + 1600;               // 400

    _Float16* B0p = (_Float16*)Y;            // 25 partials x 262,144 f16
    float* H    = R;                         // 819,200 fl
    _Float16* CPH = (_Float16*)(R + 819200); // 4 x 819,200 f16 = 1,638,400 fl
    _Float16* CSH = (_Float16*)(R + 2457600);// 819,200 f16 = 409,600 fl

    _Float16* APAD = (_Float16*)R;           // [2*25][8][136][136] f16 (front-end only)
    _Float16* X0  = (_Float16*)X0f;
    _Float16* X1  = (_Float16*)X1f;
    _Float16* WT0 = (_Float16*)WT0f;
    _Float16* WT1c= (_Float16*)WT1cf;
    _Float16* WT1 = (_Float16*)WT1f;
    _Float16* WT2 = (_Float16*)WT2f;
    _Float16* XT  = (_Float16*)XTf;

    // ---- front-end ----
    (void)hipMemsetAsync(APAD, 0, (size_t)7398400 * sizeof(_Float16), stream);
    (void)hipMemsetAsync(X0, 0, (size_t)1166848 * sizeof(_Float16), stream);
    (void)hipMemsetAsync(X1, 0, (size_t)583424 * sizeof(_Float16), stream);
    (void)hipMemsetAsync(XT, 0, (size_t)1308672 * sizeof(_Float16), stream);
    xpack0_kernel<<<1024, 256, 0, stream>>>(x, X0);
    repack_w00_kernel<<<196, 256, 0, stream>>>(conv00_w, WT0);
    repack_w1_kernel<<<98, 256, 0, stream>>>(conv1_w, WT1c);
    repack_w_kernel<<<900, 256, 0, stream>>>(w_inh, WT1);
    repack_w_kernel<<<900, 256, 0, stream>>>(w_exc, WT2);

    conv3d00_mfma<<<2048, 128, 0, stream>>>(X0, WT0, APAD);
    conv3d0_direct<<<dim3(8, 25, 16), 128, 0, stream>>>(APAD, conv0_w, B0p);
    xpack1_kernel<<<1024, 256, 0, stream>>>(B0p, X1);
    conv3d1_mfma<<<2048, 128, 0, stream>>>(X1, WT1c, conv1_b, Y);

    // ---- recurrence ----
    (void)hipMemsetAsync(H, 0, (size_t)NELEM * sizeof(float), stream);
    for (int t = 0; t < 8; ++t) {
        conv2d15_mfma<<<dim3(64, 4), 256, 0, stream>>>(XT, WT1, CPH);
        bnstats1_kernel<<<dim3(25, 8), 256, 0, stream>>>(CPH, CSH, (float2*)PS);
        nsg_kernel<<<256, 256, 0, stream>>>(Y, H, CSH, (const float2*)PS, bn1_w, bn1_b,
                                            alpha, mu, XT, t);
        conv2d15_mfma<<<dim3(64, 4), 256, 0, stream>>>(XT, WT2, CPH);
        bnstats1_kernel<<<dim3(25, 8), 256, 0, stream>>>(CPH, CSH, (float2*)PS);
        hg_kernel<<<256, 256, 0, stream>>>(H, CSH, (const float2*)PS, bn3_w, bn3_b,
                                           kappa, gamma_p, w_mix, u1_w, u1_b,
                                           u2_w, u2_b, XT);
    }

    // ---- head ----
    bnstats_head_kernel<<<dim3(25, 8), 256, 0, stream>>>(H, (float2*)PS);
    fc1_kernel<<<800, 256, 0, stream>>>(H, (const float2*)PS, bn_out_w, bn_out_b,
                                        fc4_w, (float2*)PART);
    fc2_kernel<<<1, 256, 0, stream>>>((const float2*)PART, fc4_b, (float*)d_out);
}

// Round 16
// 918.409 us; speedup vs baseline: 1.2302x; 1.2302x over previous
//
#include <hip/hip_runtime.h>
#include <cstddef>

#define HW 16384           // 128*128
#define NELEM 819200       // 2*25*HW

// XT layout: [b][row 142][ks 2][half 2][px 144][8ch]
#define XT_ROW 4608
#define XT_KS  2304
#define XT_HALF 1152

typedef _Float16 f16x8 __attribute__((ext_vector_type(8)));
typedef _Float16 f16x4 __attribute__((ext_vector_type(4)));
typedef _Float16 f16x2 __attribute__((ext_vector_type(2)));
typedef float    f32x16 __attribute__((ext_vector_type(16)));

#define MFMA32(a, b, c) __builtin_amdgcn_mfma_f32_32x32x16_f16((a), (b), (c), 0, 0, 0)

#if __has_builtin(__builtin_amdgcn_fdot2)
#define HAS_FDOT2 1
#else
#define HAS_FDOT2 0
#endif

__device__ __forceinline__ float sp_f(float x) {
    return fmaxf(x, 0.f) + log1pf(expf(-fabsf(x)));
}
__device__ __forceinline__ float sig_f(float x) {
    return 1.f / (1.f + expf(-x));
}

// ---------------- front-end prepack kernels ----------------
__global__ __launch_bounds__(256) void xpack0_kernel(
    const float* __restrict__ x, _Float16* __restrict__ x0)
{
    const int p = blockIdx.x * 256 + threadIdx.x;   // < 262144
    const int b = p >> 17, rem = p & 131071;
    const int z = rem >> 14, pix = rem & 16383;
    const int y = pix >> 7, xx = pix & 127;
    const size_t sb = ((size_t)b * 3 * 8 + z) << 14;
    f16x4 v;
    v[0] = (_Float16)x[sb + pix];
    v[1] = (_Float16)x[sb + (8ull << 14) + pix];
    v[2] = (_Float16)x[sb + (16ull << 14) + pix];
    v[3] = (_Float16)0.f;
    *(f16x4*)(x0 + (((size_t)(b * 8 + z) * 134 + y + 3) * 136 + xx + 3) * 4) = v;
}

__global__ __launch_bounds__(256) void repack_w00_kernel(
    const float* __restrict__ w, _Float16* __restrict__ wt)
{
    const int idx = blockIdx.x * 256 + threadIdx.x;   // < 50176
    const int j  = idx & 7;
    const int m  = (idx >> 3) & 31;
    const int h  = (idx >> 8) & 1;
    const int kk = (idx >> 9) & 1;
    const int tapb = idx >> 10;                       // dz*7+dy, < 49
    const int dz = tapb / 7, dy = tapb - dz * 7;
    const int ic = j & 3, dxl = j >> 2;
    const int dx = kk * 4 + h * 2 + dxl;
    float v = 0.f;
    if (m < 25 && ic < 3 && dx < 7)
        v = w[(((m * 3 + ic) * 7 + dz) * 7 + dy) * 7 + dx];
    wt[idx] = (_Float16)v;
}

__global__ __launch_bounds__(256) void xpack1_kernel(
    const _Float16* __restrict__ b0p, _Float16* __restrict__ x1)
{
    const int p = blockIdx.x * 256 + threadIdx.x;   // < 262144
    const int b = p >> 17, rem = p & 131071;
    const int z = rem >> 14, pix = rem & 16383;
    const int y = pix >> 7, xx = pix & 127;
    float s = 0.f;
    #pragma unroll
    for (int g = 0; g < 25; ++g) s += (float)b0p[(size_t)g * 262144 + p];
    x1[(((size_t)(b * 8 + z) * 134 + y + 3) * 136 + xx + 3) * 2] = (_Float16)s;
}

__global__ __launch_bounds__(256) void repack_w1_kernel(
    const float* __restrict__ w, _Float16* __restrict__ wt)
{
    const int idx = blockIdx.x * 256 + threadIdx.x;   // < 25088
    const int j = idx & 7;
    const int m = (idx >> 3) & 31;
    const int h = (idx >> 8) & 1;
    const int tapb = idx >> 9;                        // < 49
    const int dz = tapb / 7, dy = tapb - dz * 7;
    const int c2 = j & 1, dx = h * 4 + (j >> 1);
    float v = 0.f;
    if (m < 25 && c2 == 0 && dx < 7)
        v = w[((m * 7 + dz) * 7 + dy) * 7 + dx];
    wt[idx] = (_Float16)v;
}

// ---------------- conv00 via MFMA: 3ch -> 25ch, writes halo-4-padded f16 planes ----
__global__ __launch_bounds__(128) void conv3d00_mfma(
    const _Float16* __restrict__ x0, const _Float16* __restrict__ wt0,
    _Float16* __restrict__ apad)
{
    const int g = blockIdx.x;
    const int b = g >> 10;
    const int zo = (g >> 7) & 7;
    const int y = g & 127;
    const int tid = threadIdx.x;
    const int wv = tid >> 6;
    const int lane = tid & 63;
    const int n = lane & 31;
    const int h = lane >> 5;
    const int xc = wv << 6;

    f32x16 acc0, acc1;
    #pragma unroll
    for (int i = 0; i < 16; ++i) { acc0[i] = 0.f; acc1[i] = 0.f; }

    for (int dz = 0; dz < 7; ++dz) {
        const int zin = zo + dz - 3;
        if (zin < 0 || zin >= 8) continue;
        const _Float16* xpl = x0 + (size_t)(b * 8 + zin) * (134 * 136 * 4);
        #pragma unroll
        for (int dy = 0; dy < 7; ++dy) {
            const _Float16* xr = xpl + (size_t)(y + dy) * (136 * 4);
            const _Float16* wb = wt0 + (size_t)((dz * 7 + dy) * 2) * 512 + h * 256 + n * 8;
            f16x8 a0 = *(const f16x8*)(wb);
            f16x8 a1 = *(const f16x8*)(wb + 512);
            const _Float16* bp = xr + (size_t)(xc + n + 2 * h) * 4;
            f16x8 b00 = *(const f16x8*)(bp);
            f16x8 b01 = *(const f16x8*)(bp + 16);
            f16x8 b10 = *(const f16x8*)(bp + 128);
            f16x8 b11 = *(const f16x8*)(bp + 144);
            acc0 = MFMA32(a0, b00, acc0);
            acc1 = MFMA32(a0, b10, acc1);
            acc0 = MFMA32(a1, b01, acc0);
            acc1 = MFMA32(a1, b11, acc1);
        }
    }
    _Float16* ob = apad + (size_t)((b * 25) * 8 + zo) * 18496
                 + (size_t)(y + 4) * 136 + 4 + xc + n;
    #pragma unroll
    for (int r = 0; r < 16; ++r) {
        const int row = (r & 3) + 8 * (r >> 2) + 4 * h;
        if (row < 25) {
            ob[(size_t)row * 147968]      = (_Float16)acc0[r];
            ob[(size_t)row * 147968 + 32] = (_Float16)acc1[r];
        }
    }
}

// ---------------- conv0: 25ch -> 1ch, direct-global f16 reads, fdot2, f16 partials ----
__global__ __launch_bounds__(128) void conv3d0_direct(
    const _Float16* __restrict__ apad, const float* __restrict__ wgt,
    _Float16* __restrict__ out)
{
    const int y0 = blockIdx.x * 16;
    const int ic = blockIdx.y;
    const int b  = blockIdx.z >> 3;
    const int zo = blockIdx.z & 7;
    const int tid = threadIdx.x, tx = tid & 15, ty = tid >> 4;

    float acc0[8] = {0,0,0,0,0,0,0,0};
    float acc1[8] = {0,0,0,0,0,0,0,0};
    const float* wb0 = wgt + ic * 343;

    for (int dz = 0; dz < 7; ++dz) {
        const int zin = zo + dz - 3;
        if (zin < 0 || zin >= 8) continue;
        const _Float16* pl = apad + (size_t)((b * 25 + ic) * 8 + zin) * 18496
                           + (size_t)(y0 + (ty << 1) + 1) * 136 + (tx << 3);
        const float* wb = wb0 + dz * 49;
#if HAS_FDOT2
        f16x2 wpn[4], wpo[4];
        #pragma unroll
        for (int j = 0; j <= 7; ++j) {
            f16x8 r0 = *(const f16x8*)(pl + (size_t)j * 136);
            f16x8 r1 = *(const f16x8*)(pl + (size_t)j * 136 + 8);
            _Float16 rr[16];
            #pragma unroll
            for (int i = 0; i < 8; ++i) { rr[i] = r0[i]; rr[8 + i] = r1[i]; }
            f16x2 pr[14];
            #pragma unroll
            for (int i = 0; i < 14; ++i) { pr[i][0] = rr[i + 1]; pr[i][1] = rr[i + 2]; }
            if (j <= 6) {
                #pragma unroll
                for (int p = 0; p < 3; ++p) {
                    wpn[p][0] = (_Float16)wb[j * 7 + 2 * p];
                    wpn[p][1] = (_Float16)wb[j * 7 + 2 * p + 1];
                }
                wpn[3][0] = (_Float16)wb[j * 7 + 6];
                wpn[3][1] = (_Float16)0.f;
            }
            #pragma unroll
            for (int k = 0; k < 8; ++k) {
                if (j <= 6) {
                    #pragma unroll
                    for (int p = 0; p < 4; ++p)
                        acc0[k] = __builtin_amdgcn_fdot2(wpn[p], pr[k + 2 * p], acc0[k], false);
                }
                if (j >= 1) {
                    #pragma unroll
                    for (int p = 0; p < 4; ++p)
                        acc1[k] = __builtin_amdgcn_fdot2(wpo[p], pr[k + 2 * p], acc1[k], false);
                }
            }
            #pragma unroll
            for (int p = 0; p < 4; ++p) wpo[p] = wpn[p];
        }
#else
        float wn[7], wo[7];
        #pragma unroll
        for (int j = 0; j <= 7; ++j) {
            f16x8 r0 = *(const f16x8*)(pl + (size_t)j * 136);
            f16x8 r1 = *(const f16x8*)(pl + (size_t)j * 136 + 8);
            float rrf[16];
            #pragma unroll
            for (int i = 0; i < 8; ++i) { rrf[i] = (float)r0[i]; rrf[8 + i] = (float)r1[i]; }
            if (j <= 6) {
                #pragma unroll
                for (int d = 0; d < 7; ++d) wn[d] = wb[j * 7 + d];
            }
            #pragma unroll
            for (int dx = 0; dx < 7; ++dx) {
                if (j <= 6) {
                    float w0 = wn[dx];
                    #pragma unroll
                    for (int k = 0; k < 8; ++k) acc0[k] = fmaf(rrf[dx + k + 1], w0, acc0[k]);
                }
                if (j >= 1) {
                    float w1 = wo[dx];
                    #pragma unroll
                    for (int k = 0; k < 8; ++k) acc1[k] = fmaf(rrf[dx + k + 1], w1, acc1[k]);
                }
            }
            #pragma unroll
            for (int d = 0; d < 7; ++d) wo[d] = wn[d];
        }
#endif
    }
    _Float16* op = out + (size_t)ic * 262144
              + (((size_t)(b * 8 + zo)) << 14) + ((size_t)(y0 + (ty << 1)) << 7) + (tx << 3);
    f16x8 o0, o1;
    #pragma unroll
    for (int k = 0; k < 8; ++k) { o0[k] = (_Float16)acc0[k]; o1[k] = (_Float16)acc1[k]; }
    *(f16x8*)op = o0;
    *(f16x8*)(op + 128) = o1;
}

// ---------------- conv1 via MFMA: 1ch -> 25ch, bias+square fused ----------------
__global__ __launch_bounds__(128) void conv3d1_mfma(
    const _Float16* __restrict__ x1, const _Float16* __restrict__ wt1,
    const float* __restrict__ bias, float* __restrict__ out)
{
    const int g = blockIdx.x;
    const int b = g >> 10;
    const int zo = (g >> 7) & 7;
    const int y = g & 127;
    const int tid = threadIdx.x;
    const int wv = tid >> 6;
    const int lane = tid & 63;
    const int n = lane & 31;
    const int h = lane >> 5;
    const int xc = wv << 6;

    f32x16 acc0, acc1;
    #pragma unroll
    for (int i = 0; i < 16; ++i) { acc0[i] = 0.f; acc1[i] = 0.f; }

    for (int dz = 0; dz < 7; ++dz) {
        const int zin = zo + dz - 3;
        if (zin < 0 || zin >= 8) continue;
        const _Float16* xpl = x1 + (size_t)(b * 8 + zin) * (134 * 136 * 2);
        #pragma unroll
        for (int dy = 0; dy < 7; ++dy) {
            const _Float16* wb = wt1 + (size_t)(dz * 7 + dy) * 512 + h * 256 + n * 8;
            f16x8 a0 = *(const f16x8*)(wb);
            const _Float16* bp = xpl + ((size_t)(y + dy) * 136 + xc + n) * 2 + h * 8;
            f16x8 b0 = *(const f16x8*)(bp);
            f16x8 b1 = *(const f16x8*)(bp + 64);
            acc0 = MFMA32(a0, b0, acc0);
            acc1 = MFMA32(a0, b1, acc1);
        }
    }
    float* ob = out + ((((size_t)b * 25) * 8 + zo) << 14) + (y << 7) + xc + n;
    #pragma unroll
    for (int r = 0; r < 16; ++r) {
        const int row = (r & 3) + 8 * (r >> 2) + 4 * h;
        if (row < 25) {
            float v0 = acc0[r] + bias[row];
            float v1 = acc1[r] + bias[row];
            ob[(size_t)row * 131072]      = v0 * v0;
            ob[(size_t)row * 131072 + 32] = v1 * v1;
        }
    }
}

// ---------------- weight repack for 15x15 (A-frag) ----------------
__global__ __launch_bounds__(256) void repack_w_kernel(
    const float* __restrict__ w, _Float16* __restrict__ wt)
{
    const int idx = blockIdx.x * 256 + threadIdx.x;   // < 230400
    const int j    = idx & 7;
    const int m    = (idx >> 3) & 31;
    const int half = (idx >> 8) & 1;
    const int ks   = (idx >> 9) & 1;
    const int t    = idx >> 10;                       // t = ky*15+kx, < 225
    const int ic   = ks * 16 + half * 8 + j;
    float v = 0.f;
    if (m < 25 && ic < 25) v = w[(m * 25 + ic) * 225 + t];
    wt[idx] = (_Float16)v;
}

// ---------------- 2D conv 15x15 v5: kg=4, B-row register rolling, dbuf LDS A ----
template<int NKY>
__device__ __forceinline__ void conv15_core_v5(
    const _Float16* __restrict__ xb, const _Float16* __restrict__ wtk,
    _Float16* lA, int tid, int bRow0, int xg, int n, int half,
    f32x16& accA, f32x16& accB, f32x16& accC, f32x16& accD)
{
    #pragma unroll
    for (int j = 0; j <= NKY; ++j) {
        if (j < NKY) {
            if (j > 0) __syncthreads();
            _Float16* dst = lA + (size_t)(j & 1) * 15360;
            const _Float16* src = wtk + (size_t)j * 15360;
            #pragma unroll
            for (int p = 0; p < 8; ++p) {
                const int g = p * 256 + tid;
                if (g < 1920)
                    *(f16x8*)(dst + (size_t)g * 8) = *(const f16x8*)(src + (size_t)g * 8);
            }
            __syncthreads();
        }
        const _Float16* br = xb + (size_t)(bRow0 + j) * XT_ROW
                           + (size_t)half * XT_HALF + (size_t)(xg + n) * 8;
        const _Float16* lc = lA + (size_t)(j & 1) * 15360 + half * 256 + n * 8;
        const _Float16* lp = lA + (size_t)((j - 1) & 1) * 15360 + half * 256 + n * 8;
        #pragma unroll
        for (int kx = 0; kx < 15; ++kx) {
            const _Float16* p0 = br + kx * 8;
            f16x8 b00 = *(const f16x8*)(p0);
            f16x8 b01 = *(const f16x8*)(p0 + XT_KS);
            f16x8 b10 = *(const f16x8*)(p0 + 256);
            f16x8 b11 = *(const f16x8*)(p0 + XT_KS + 256);
            if (j < NKY) {
                f16x8 a0 = *(const f16x8*)(lc + kx * 1024);
                f16x8 a1 = *(const f16x8*)(lc + kx * 1024 + 512);
                accA = MFMA32(a0, b00, accA); accA = MFMA32(a1, b01, accA);
                accB = MFMA32(a0, b10, accB); accB = MFMA32(a1, b11, accB);
            }
            if (j >= 1) {
                f16x8 q0 = *(const f16x8*)(lp + kx * 1024);
                f16x8 q1 = *(const f16x8*)(lp + kx * 1024 + 512);
                accC = MFMA32(q0, b00, accC); accC = MFMA32(q1, b01, accC);
                accD = MFMA32(q0, b10, accD); accD = MFMA32(q1, b11, accD);
            }
        }
    }
}

__global__ __launch_bounds__(256) void conv2d15_mfma(
    const _Float16* __restrict__ xt, const _Float16* __restrict__ wt,
    _Float16* __restrict__ cph)
{
    const int blk = blockIdx.x;          // 64: b*32 + rq
    const int b   = blk >> 5;
    const int rq  = blk & 31;
    const int kg  = blockIdx.y;          // 0..3

    __shared__ __align__(16) _Float16 lA[30720];   // 2 x 30 KB double buffer

    const int tid  = threadIdx.x;
    const int w    = tid >> 6;
    const int lane = tid & 63;
    const int n    = lane & 31;
    const int half = lane >> 5;
    const int xg   = (w & 1) << 6;
    const int y0w  = rq * 4 + ((w >> 1) << 1);

    f32x16 accA, accB, accC, accD;
    #pragma unroll
    for (int i = 0; i < 16; ++i) { accA[i] = 0.f; accB[i] = 0.f; accC[i] = 0.f; accD[i] = 0.f; }

    const int ky0 = (kg < 3) ? kg * 4 : 12;
    const _Float16* xb = xt + (size_t)(b * 142) * XT_ROW;
    const _Float16* wtk = wt + (size_t)ky0 * 15360;
    const int bRow0 = y0w + ky0;

    if (kg < 3) conv15_core_v5<4>(xb, wtk, lA, tid, bRow0, xg, n, half, accA, accB, accC, accD);
    else        conv15_core_v5<3>(xb, wtk, lA, tid, bRow0, xg, n, half, accA, accB, accC, accD);

    _Float16* ob = cph + (size_t)kg * NELEM + (((size_t)b * 25) << 14) + (y0w << 7) + xg + n;
    #pragma unroll
    for (int r = 0; r < 16; ++r) {
        const int oc = (r & 3) + 8 * (r >> 2) + 4 * half;
        if (oc < 25) {
            _Float16* p = ob + ((size_t)oc << 14);
            p[0]   = (_Float16)accA[r];
            p[32]  = (_Float16)accB[r];
            p[128] = (_Float16)accC[r];
            p[160] = (_Float16)accD[r];
        }
    }
}

// ---------------- BN stats stage 1: sum 4 f16 partials -> f16 CS + PS (shuffle) ----
__global__ __launch_bounds__(256) void bnstats1_kernel(
    const _Float16* __restrict__ cph, _Float16* __restrict__ csh,
    float2* __restrict__ ps)
{
    const int c = blockIdx.x;     // 25
    const int s = blockIdx.y;     // 8
    const int tid = threadIdx.x;
    float s1 = 0.f, s2 = 0.f;
    #pragma unroll
    for (int bb = 0; bb < 2; ++bb) {
        const size_t plane = ((size_t)(bb * 25 + c)) << 14;
        #pragma unroll
        for (int i = 0; i < 2; ++i) {
            const size_t e = plane + ((size_t)(s * 512 + tid + i * 256)) * 4;
            float4 v = make_float4(0.f, 0.f, 0.f, 0.f);
            #pragma unroll
            for (int p = 0; p < 4; ++p) {
                f16x4 q = *(const f16x4*)(cph + (size_t)p * NELEM + e);
                v.x += (float)q[0]; v.y += (float)q[1]; v.z += (float)q[2]; v.w += (float)q[3];
            }
            f16x4 o;
            o[0] = (_Float16)v.x; o[1] = (_Float16)v.y; o[2] = (_Float16)v.z; o[3] = (_Float16)v.w;
            *(f16x4*)(csh + e) = o;
            s1 += v.x + v.y + v.z + v.w;
            s2 += v.x * v.x + v.y * v.y + v.z * v.z + v.w * v.w;
        }
    }
    #pragma unroll
    for (int off = 32; off; off >>= 1) { s1 += __shfl_down(s1, off); s2 += __shfl_down(s2, off); }
    __shared__ float a1[4], a2[4];
    if ((tid & 63) == 0) { a1[tid >> 6] = s1; a2[tid >> 6] = s2; }
    __syncthreads();
    if (tid == 0)
        ps[c * 8 + s] = make_float2(a1[0] + a1[1] + a1[2] + a1[3],
                                    a2[0] + a2[1] + a2[2] + a2[3]);
}

// ---------------- fused ns1, 4-way channel split (slot = wave): XT = f16(ns1) ----
// 512 blocks x 256 thr; slot owns one 16B XT chunk (8 channels; slot3: ch24 only).
__global__ __launch_bounds__(256) void nsg_kernel(
    const float* __restrict__ y, const float* __restrict__ h,
    const _Float16* __restrict__ csh, const float2* __restrict__ ps,
    const float* __restrict__ gw, const float* __restrict__ gb,
    const float* __restrict__ alpha, const float* __restrict__ mu,
    _Float16* __restrict__ xt, int t)
{
    __shared__ float sc[25], sh[25];
    const int tid = threadIdx.x;
    if (tid < 25) {
        float s1 = 0.f, s2 = 0.f;
        #pragma unroll
        for (int s = 0; s < 8; ++s) { float2 v = ps[tid * 8 + s]; s1 += v.x; s2 += v.y; }
        const float m = s1 * (1.f / 32768.f);
        const float var = fmaxf(s2 * (1.f / 32768.f) - m * m, 0.f);
        const float scv = gw[tid] * rsqrtf(var + 1e-3f);
        sc[tid] = scv;
        sh[tid] = gb[tid] - m * scv;
    }
    __syncthreads();
    const int slot = tid >> 6;                      // 0..3
    const int p = blockIdx.x * 64 + (tid & 63);     // < 32768
    const int b = p >> 14, pix = p & (HW - 1);
    const size_t base = (((size_t)b * 25) << 14) + pix;
    const int c0 = slot << 3;
    __align__(16) _Float16 xv[8];
    #pragma unroll
    for (int k = 0; k < 8; ++k) xv[k] = (_Float16)0.f;
    if (slot < 3) {
        #pragma unroll
        for (int k = 0; k < 8; ++k) {
            const int c = c0 + k;
            const size_t idx = base + ((size_t)c << 14);
            const float yv = y[(((size_t)(b * 25 + c) * 8 + t) << 14) + pix];
            const float c1n = (float)csh[idx] * sc[c] + sh[c];
            const float pre = c1n * (alpha[c] * h[idx] + mu[c]);
            xv[k] = (_Float16)sp_f(yv - sp_f(pre));
        }
    } else {
        const int c = 24;
        const size_t idx = base + ((size_t)c << 14);
        const float yv = y[(((size_t)(b * 25 + c) * 8 + t) << 14) + pix];
        const float c1n = (float)csh[idx] * sc[c] + sh[c];
        const float pre = c1n * (alpha[c] * h[idx] + mu[c]);
        xv[0] = (_Float16)sp_f(yv - sp_f(pre));
    }
    const int yy = pix >> 7, xx = pix & 127;
    _Float16* xp = xt + (size_t)(b * 142 + yy + 7) * XT_ROW + (size_t)(xx + 7) * 8
                 + (size_t)(slot >> 1) * XT_KS + (size_t)(slot & 1) * XT_HALF;
    *(float4*)xp = *((const float4*)xv);
}

// ---------------- fused hnew + both gates, 4-way channel split w/ LDS staging ----
__global__ __launch_bounds__(256) void hg_kernel(
    float* __restrict__ h, const _Float16* __restrict__ csh,
    const float2* __restrict__ ps, const float* __restrict__ gw,
    const float* __restrict__ gb, const float* __restrict__ kappa,
    const float* __restrict__ gp, const float* __restrict__ wmix,
    const float* __restrict__ u1w, const float* __restrict__ u1b,
    const float* __restrict__ u2w, const float* __restrict__ u2b,
    _Float16* __restrict__ xt)
{
    __shared__ float sc[25], sh[25];
    __shared__ float nvs[64 * 26];
    __shared__ float hvs[64 * 26];
    const int tid = threadIdx.x;
    if (tid < 25) {
        float s1 = 0.f, s2 = 0.f;
        #pragma unroll
        for (int s = 0; s < 8; ++s) { float2 v = ps[tid * 8 + s]; s1 += v.x; s2 += v.y; }
        const float m = s1 * (1.f / 32768.f);
        const float var = fmaxf(s2 * (1.f / 32768.f) - m * m, 0.f);
        const float scv = gw[tid] * rsqrtf(var + 1e-3f);
        sc[tid] = scv;
        sh[tid] = gb[tid] - m * scv;
    }
    const int slot = tid >> 6;
    const int lpix = tid & 63;
    const int p = blockIdx.x * 64 + lpix;   // < 32768
    const int b = p >> 14, pix = p & (HW - 1);
    const size_t base = (((size_t)b * 25) << 14) + pix;
    const int yy = pix >> 7, xx = pix & 127;
    _Float16* xp = xt + (size_t)(b * 142 + yy + 7) * XT_ROW + (size_t)(xx + 7) * 8
                 + (size_t)(slot >> 1) * XT_KS + (size_t)(slot & 1) * XT_HALF;
    const int c0 = slot << 3;
    const int nc = (slot < 3) ? 8 : 1;
    float* nvr = nvs + lpix * 26;
    float* hvr = hvs + lpix * 26;

    // Phase A: nv from own XT chunk -> LDS
    __align__(16) _Float16 nvh[8];
    *(float4*)nvh = *(const float4*)xp;
    for (int k = 0; k < nc; ++k) nvr[c0 + k] = (float)nvh[k];
    __syncthreads();

    // Phase B: gate2 from LDS nv; hnew for own channels; stage hv
    for (int k = 0; k < nc; ++k) {
        const int c = c0 + k;
        float acc = u2b[c];
        #pragma unroll
        for (int ic = 0; ic < 25; ++ic) acc += u2w[c * 25 + ic] * nvr[ic];
        const float g = sig_f(acc);
        const size_t idx = base + ((size_t)c << 14);
        const float c2n = (float)csh[idx] * sc[c] + sh[c];
        const float n = nvr[c];
        const float h2 = sp_f(kappa[c] * n + gp[c] * c2n + wmix[c] * n * c2n);
        const float hn = sp_f((1.f - g) * h[idx] + g * h2);
        h[idx] = hn;
        hvr[c] = hn;
    }
    __syncthreads();

    // Phase C: gate1 from LDS hv; write own XT chunk
    __align__(16) _Float16 xv[8];
    #pragma unroll
    for (int k = 0; k < 8; ++k) xv[k] = (_Float16)0.f;
    for (int k = 0; k < nc; ++k) {
        const int c = c0 + k;
        float acc = u1b[c];
        #pragma unroll
        for (int ic = 0; ic < 25; ++ic) acc += u1w[c * 25 + ic] * hvr[ic];
        xv[k] = (_Float16)(hvr[c] * sig_f(acc));
    }
    *(float4*)xp = *((const float4*)xv);
}

// ---------------- head: BN stats over H (f32) ----------------
__global__ __launch_bounds__(256) void bnstats_head_kernel(
    const float* __restrict__ x, float2* __restrict__ ps)
{
    const int c = blockIdx.x;     // 25
    const int s = blockIdx.y;     // 8
    const int tid = threadIdx.x;
    float s1 = 0.f, s2 = 0.f;
    #pragma unroll
    for (int bb = 0; bb < 2; ++bb) {
        const size_t plane = ((size_t)(bb * 25 + c)) << 14;
        const float4* p0 = (const float4*)(x + plane) + s * 512;
        #pragma unroll
        for (int i = 0; i < 2; ++i) {
            float4 v = p0[tid + i * 256];
            s1 += v.x + v.y + v.z + v.w;
            s2 += v.x * v.x + v.y * v.y + v.z * v.z + v.w * v.w;
        }
    }
    #pragma unroll
    for (int off = 32; off; off >>= 1) { s1 += __shfl_down(s1, off); s2 += __shfl_down(s2, off); }
    __shared__ float a1[4], a2[4];
    if ((tid & 63) == 0) { a1[tid >> 6] = s1; a2[tid >> 6] = s2; }
    __syncthreads();
    if (tid == 0)
        ps[c * 8 + s] = make_float2(a1[0] + a1[1] + a1[2] + a1[3],
                                    a2[0] + a2[1] + a2[2] + a2[3]);
}

// ---------------- fused BN finalize + bn_out + avgpool2 + fc partial dot ----------------
__global__ __launch_bounds__(256) void fc1_kernel(
    const float* __restrict__ h, const float2* __restrict__ ps,
    const float* __restrict__ gw, const float* __restrict__ gb,
    const float* __restrict__ fcw, float2* __restrict__ part)
{
    __shared__ float sc[25], sh[25];
    const int tid = threadIdx.x;
    if (tid < 25) {
        float s1 = 0.f, s2 = 0.f;
        #pragma unroll
        for (int s = 0; s < 8; ++s) { float2 v = ps[tid * 8 + s]; s1 += v.x; s2 += v.y; }
        const float m = s1 * (1.f / 32768.f);
        const float var = fmaxf(s2 * (1.f / 32768.f) - m * m, 0.f);
        const float scv = gw[tid] * rsqrtf(var + 1e-3f);
        sc[tid] = scv;
        sh[tid] = gb[tid] - m * scv;
    }
    __syncthreads();
    const int i = blockIdx.x * 256 + tid;   // < 204800
    int px = i & 63;
    int t = i >> 6;
    int py = t & 63; t >>= 6;               // t = b*25 + c
    int c = t >= 25 ? t - 25 : t;
    const float* hp = h + ((size_t)t << 14);
    const int y0 = py << 1, xg = px << 1;
    float s = hp[(y0 << 7) + xg] + hp[(y0 << 7) + xg + 1]
            + hp[((y0 + 1) << 7) + xg] + hp[((y0 + 1) << 7) + xg + 1];
    const float o = 0.25f * s * sc[c] + sh[c];
    float p0 = o * fcw[i];
    float p1 = o * fcw[204800 + i];
    #pragma unroll
    for (int off = 32; off; off >>= 1) { p0 += __shfl_down(p0, off); p1 += __shfl_down(p1, off); }
    __shared__ float a0[4], a1[4];
    if ((tid & 63) == 0) { a0[tid >> 6] = p0; a1[tid >> 6] = p1; }
    __syncthreads();
    if (tid == 0)
        part[blockIdx.x] = make_float2(a0[0] + a0[1] + a0[2] + a0[3],
                                       a1[0] + a1[1] + a1[2] + a1[3]);
}

__global__ __launch_bounds__(256) void fc2_kernel(
    const float2* __restrict__ part, const float* __restrict__ fcb, float* __restrict__ out)
{
    const int tid = threadIdx.x;
    float s0 = 0.f, s1 = 0.f;
    for (int i = tid; i < 800; i += 256) { float2 v = part[i]; s0 += v.x; s1 += v.y; }
    #pragma unroll
    for (int off = 32; off; off >>= 1) { s0 += __shfl_down(s0, off); s1 += __shfl_down(s1, off); }
    __shared__ float a0[4], a1[4];
    if ((tid & 63) == 0) { a0[tid >> 6] = s0; a1[tid >> 6] = s1; }
    __syncthreads();
    if (tid == 0) {
        out[0] = sig_f(a0[0] + a0[1] + a0[2] + a0[3] + fcb[0]);
        out[1] = sig_f(a1[0] + a1[1] + a1[2] + a1[3] + fcb[1]);
    }
}

extern "C" void kernel_launch(void* const* d_in, const int* in_sizes, int n_in,
                              void* d_out, int out_size, void* d_ws, size_t ws_size,
                              hipStream_t stream)
{
    const float* x        = (const float*)d_in[0];
    const float* conv00_w = (const float*)d_in[1];
    const float* conv0_w  = (const float*)d_in[2];
    const float* conv1_w  = (const float*)d_in[3];
    const float* conv1_b  = (const float*)d_in[4];
    const float* u1_w     = (const float*)d_in[5];
    const float* u1_b     = (const float*)d_in[6];
    const float* u2_w     = (const float*)d_in[7];
    const float* u2_b     = (const float*)d_in[8];
    const float* w_inh    = (const float*)d_in[9];
    const float* w_exc    = (const float*)d_in[10];
    const float* alpha    = (const float*)d_in[11];
    const float* mu       = (const float*)d_in[12];
    const float* gamma_p  = (const float*)d_in[13];
    const float* kappa    = (const float*)d_in[14];
    const float* w_mix    = (const float*)d_in[15];
    const float* bn1_w    = (const float*)d_in[16];
    const float* bn1_b    = (const float*)d_in[17];
    const float* bn3_w    = (const float*)d_in[18];
    const float* bn3_b    = (const float*)d_in[19];
    const float* bn_out_w = (const float*)d_in[20];
    const float* bn_out_b = (const float*)d_in[21];
    const float* fc4_w    = (const float*)d_in[22];
    const float* fc4_b    = (const float*)d_in[23];

    float* ws = (float*)d_ws;
    // layout (float offsets):
    float* Y    = ws;                        // [0, 6,553,600): B0p(f16) early, then Y
    float* R    = ws + 6553600;              // front-end: APAD; then H + CPH(4x f16) + CSH
    float* X0f  = ws + 13107200;             // X0: 583,424 fl
    float* X1f  = ws + 13690624;             // X1: 291,712 fl
    float* WT0f = ws + 13982336;             // 25,088 fl
    float* WT1cf= ws + 14007424;             // 12,544 fl
    float* WT1f = ws + 14019968;             // 115,200 fl
    float* WT2f = ws + 14135168;             // 115,200 fl
    float* XTf  = ws + 14250368;             // 654,336 fl
    float* PART = ws + 14904704;             // 1600
    float* PS   = PART + 1600;               // 400

    _Float16* B0p = (_Float16*)Y;            // 25 partials x 262,144 f16
    float* H    = R;                         // 819,200 fl
    _Float16* CPH = (_Float16*)(R + 819200); // 4 x 819,200 f16 = 1,638,400 fl
    _Float16* CSH = (_Float16*)(R + 2457600);// 819,200 f16 = 409,600 fl

    _Float16* APAD = (_Float16*)R;           // [2*25][8][136][136] f16 (front-end only)
    _Float16* X0  = (_Float16*)X0f;
    _Float16* X1  = (_Float16*)X1f;
    _Float16* WT0 = (_Float16*)WT0f;
    _Float16* WT1c= (_Float16*)WT1cf;
    _Float16* WT1 = (_Float16*)WT1f;
    _Float16* WT2 = (_Float16*)WT2f;
    _Float16* XT  = (_Float16*)XTf;

    // ---- front-end ----
    (void)hipMemsetAsync(APAD, 0, (size_t)7398400 * sizeof(_Float16), stream);
    (void)hipMemsetAsync(X0, 0, (size_t)1166848 * sizeof(_Float16), stream);
    (void)hipMemsetAsync(X1, 0, (size_t)583424 * sizeof(_Float16), stream);
    (void)hipMemsetAsync(XT, 0, (size_t)1308672 * sizeof(_Float16), stream);
    xpack0_kernel<<<1024, 256, 0, stream>>>(x, X0);
    repack_w00_kernel<<<196, 256, 0, stream>>>(conv00_w, WT0);
    repack_w1_kernel<<<98, 256, 0, stream>>>(conv1_w, WT1c);
    repack_w_kernel<<<900, 256, 0, stream>>>(w_inh, WT1);
    repack_w_kernel<<<900, 256, 0, stream>>>(w_exc, WT2);

    conv3d00_mfma<<<2048, 128, 0, stream>>>(X0, WT0, APAD);
    conv3d0_direct<<<dim3(8, 25, 16), 128, 0, stream>>>(APAD, conv0_w, B0p);
    xpack1_kernel<<<1024, 256, 0, stream>>>(B0p, X1);
    conv3d1_mfma<<<2048, 128, 0, stream>>>(X1, WT1c, conv1_b, Y);

    // ---- recurrence ----
    (void)hipMemsetAsync(H, 0, (size_t)NELEM * sizeof(float), stream);
    for (int t = 0; t < 8; ++t) {
        conv2d15_mfma<<<dim3(64, 4), 256, 0, stream>>>(XT, WT1, CPH);
        bnstats1_kernel<<<dim3(25, 8), 256, 0, stream>>>(CPH, CSH, (float2*)PS);
        nsg_kernel<<<512, 256, 0, stream>>>(Y, H, CSH, (const float2*)PS, bn1_w, bn1_b,
                                            alpha, mu, XT, t);
        conv2d15_mfma<<<dim3(64, 4), 256, 0, stream>>>(XT, WT2, CPH);
        bnstats1_kernel<<<dim3(25, 8), 256, 0, stream>>>(CPH, CSH, (float2*)PS);
        hg_kernel<<<512, 256, 0, stream>>>(H, CSH, (const float2*)PS, bn3_w, bn3_b,
                                           kappa, gamma_p, w_mix, u1_w, u1_b,
                                           u2_w, u2_b, XT);
    }

    // ---- head ----
    bnstats_head_kernel<<<dim3(25, 8), 256, 0, stream>>>(H, (float2*)PS);
    fc1_kernel<<<800, 256, 0, stream>>>(H, (const float2*)PS, bn_out_w, bn_out_b,
                                        fc4_w, (float2*)PART);
    fc2_kernel<<<1, 256, 0, stream>>>((const float2*)PART, fc4_b, (float*)d_out);
}